// Round 8
// baseline (308.756 us; speedup 1.0000x reference)
//
#include <hip/hip_runtime.h>

#define NTOK 343
#define NP   352
#define SCALE 0.2041241452319315f
#define LOG2E 1.44269504088896340736f
#define VSTR 360   // VT LDS row stride (halves)
#define PSTR 40    // P buf row stride (halves)

typedef __attribute__((ext_vector_type(8))) short bf16x8;
typedef __attribute__((ext_vector_type(4))) float f32x4;

__device__ __forceinline__ unsigned short f2bf(float f){
  unsigned u = __builtin_bit_cast(unsigned, f);
  u += 0x7fffu + ((u >> 16) & 1u);
  return (unsigned short)(u >> 16);
}
__device__ __forceinline__ float bflo(unsigned u){ return __builtin_bit_cast(float, u << 16); }
__device__ __forceinline__ float bfhi(unsigned u){ return __builtin_bit_cast(float, u & 0xffff0000u); }
__device__ __forceinline__ unsigned pk2(float a, float b){
  unsigned ua = __builtin_bit_cast(unsigned, a) + 0x8000u;
  unsigned ub = __builtin_bit_cast(unsigned, b) + 0x8000u;
  return __builtin_amdgcn_perm(ub, ua, 0x07060302u);
}
__device__ __forceinline__ unsigned pkrn(float a, float b){
  return (unsigned)f2bf(a) | ((unsigned)f2bf(b) << 16);
}
// tanh-form GeLU: 8 VALU ops
__device__ __forceinline__ float gelu_fast(float v){
  float u = v * v;
  float m = v * fmaf(0.044715f, u, 1.0f);
  float t = __builtin_amdgcn_exp2f(m * 2.30211422f);
  float r = __builtin_amdgcn_rcpf(t + 1.0f);
  return fmaf(-v, r, v);
}
__device__ __forceinline__ int region(int g){ return (g < 21) ? 0 : ((g < 25) ? 1 : 2); }

// ---------------- K0: bias table, bf16, log2-domain, per-lane uint4 order ----------------
__global__ __launch_bounds__(256) void k_rpb(const float* __restrict__ tab, unsigned short* __restrict__ rpbH){
  const int bid = blockIdx.x;
  const int qt = bid % 22, t2 = bid / 22, kp = t2 % 11, h = t2 / 11;
  for (int e = threadIdx.x; e < 512; e += 256){
    int lane = e >> 3, slot = e & 7;
    int kth = slot >> 2, reg = slot & 3;
    int n = lane & 15, qd = lane >> 4;
    int i = qt * 16 + n;
    int j = (2 * kp + kth) * 16 + qd * 4 + reg;
    float v;
    if (j >= NTOK) v = -1e30f;
    else if (i >= NTOK) v = 0.f;
    else {
      int r1 = i / 49, rm = i - r1 * 49, r2 = rm / 7, r3 = rm - r2 * 7;
      int j1 = j / 49, jm = j - j1 * 49, j2 = jm / 7, j3 = jm - j2 * 7;
      int idx = 13 * ((r1 - j1) + (r2 - j2) + 12) + (r3 - j3) + 6;
      v = tab[idx * 4 + h] * LOG2E;
    }
    rpbH[(size_t)bid * 512 + e] = f2bf(v);
  }
}

// ---------------- K-wprep1: qkv weights -> A-frag layout (lives in aO region) ----------------
__global__ __launch_bounds__(256) void k_wprep1(const float* __restrict__ qw, unsigned short* __restrict__ wQ){
  int p = blockIdx.x * 256 + threadIdx.x;   // 27648 total
  int e = p & 7, m = (p >> 3) & 15, cell = p >> 7;
  int mt = cell / 12, kq = cell - mt * 12;
  wQ[p] = f2bf(qw[(kq * 8 + e) * 288 + mt * 16 + m]);
}

// ---------------- K-wprep2: proj/fc1/fc2 weights -> A-frag layout (lives in qS) ----------------
__global__ __launch_bounds__(256) void k_wprep2(
    const float* __restrict__ pw, const float* __restrict__ w1g, const float* __restrict__ w2g,
    unsigned short* __restrict__ w1F, unsigned short* __restrict__ w2F, unsigned short* __restrict__ wP)
{
  int p = blockIdx.x * 256 + threadIdx.x;   // 82944 total
  if (p < 36864){
    int e = p & 7, m = (p >> 3) & 15, cell = p >> 7;
    int mt = cell / 12, q = cell - mt * 12;
    w1F[p] = f2bf(w1g[(q * 8 + e) * 384 + mt * 16 + m]);
  } else if (p < 73728){
    int p2 = p - 36864;
    int e = p2 & 7, m = (p2 >> 3) & 15, cell = p2 >> 7;
    int omt = cell / 48, q = cell - omt * 48;
    w2F[p2] = f2bf(w2g[(q * 8 + e) * 96 + omt * 16 + m]);
  } else {
    int p3 = p - 73728;
    int e = p3 & 7, m = (p3 >> 3) & 15, cell = p3 >> 7;
    int mt = cell / 12, kq = cell - mt * 12;
    wP[p3] = f2bf(pw[(kq * 8 + e) * 96 + mt * 16 + m]);
  }
}

// ---------------- K1: MFMA LN1 + shift-gather + QKV GEMM (half-window per block) ----------------
__global__ __launch_bounds__(256, 4) void k_qkv(
    const float* __restrict__ x, const float* __restrict__ n1w, const float* __restrict__ n1b,
    const unsigned short* __restrict__ wQ, const float* __restrict__ qb,
    unsigned short* __restrict__ qS, unsigned short* __restrict__ kS, unsigned short* __restrict__ vT)
{
  __shared__ __align__(16) unsigned short xnF[11 * 12 * 16 * 8];   // 33,792 B
  const int blk = blockIdx.x, w = blk >> 1, half = blk & 1;
  const int b = w >> 6, wl = w & 63;
  const int wx = wl >> 4, wy = (wl >> 2) & 3, wz = wl & 3;
  const int tid = threadIdx.x, lane = tid & 63, wv = tid >> 6;

  const float g1 = n1w[lane], h1 = n1b[lane];
  const float g2 = (lane < 32) ? n1w[64 + lane] : 0.f;
  const float h2 = (lane < 32) ? n1b[64 + lane] : 0.f;
  for (int r = wv; r < 176; r += 4){
    int tl = half * 176 + r;
    int tok = (tl < NTOK) ? tl : NTOK - 1;
    int tx = tok / 49, rm = tok - tx * 49, ty = rm / 7, tz = rm - ty * 7;
    int sx = (wx * 7 + tx + 3) % 28, sy = (wy * 7 + ty + 3) % 28, sz = (wz * 7 + tz + 3) % 28;
    const float* xr = x + ((size_t)b * 21952 + ((sx * 28 + sy) * 28 + sz)) * 96;
    float v1 = xr[lane];
    float v2 = (lane < 32) ? xr[64 + lane] : 0.f;
    float s = v1 + v2, sq = v1 * v1 + v2 * v2;
    #pragma unroll
    for (int off = 32; off; off >>= 1){ s += __shfl_xor(s, off); sq += __shfl_xor(sq, off); }
    float mu = s * (1.f / 96.f);
    float rs = rsqrtf(sq * (1.f / 96.f) - mu * mu + 1e-5f);
    int nt = r >> 4, n = r & 15;
    xnF[((nt * 12 + (lane >> 3)) * 16 + n) * 8 + (lane & 7)] = f2bf((v1 - mu) * rs * g1 + h1);
    if (lane < 32){
      int cc = 64 + lane;
      xnF[((nt * 12 + (cc >> 3)) * 16 + n) * 8 + (cc & 7)] = f2bf((v2 - mu) * rs * g2 + h2);
    }
  }
  __syncthreads();

  const int ln = lane & 15, qd = lane >> 4;
  bf16x8 bfr[3][3];
  int nts[3], toks[3];
  #pragma unroll
  for (int t = 0; t < 3; t++){
    int nt = wv + 4 * t;
    nts[t] = (nt < 11) ? nt : -1;
    int ntc = (nt < 11) ? nt : 0;
    toks[t] = half * 176 + ntc * 16 + ln;
    #pragma unroll
    for (int ks = 0; ks < 3; ks++)
      bfr[t][ks] = *(const bf16x8*)(xnF + ((ntc * 12 + ks * 4 + qd) * 16 + ln) * 8);
  }
  for (int mt = 0; mt < 18; mt++){
    bf16x8 afr[3];
    #pragma unroll
    for (int ks = 0; ks < 3; ks++)
      afr[ks] = *(const bf16x8*)(wQ + ((mt * 12 + ks * 4 + qd) * 16 + ln) * 8);
    f32x4 acc[3];
    #pragma unroll
    for (int t = 0; t < 3; t++){ acc[t][0] = 0.f; acc[t][1] = 0.f; acc[t][2] = 0.f; acc[t][3] = 0.f; }
    #pragma unroll
    for (int ks = 0; ks < 3; ks++)
      #pragma unroll
      for (int t = 0; t < 3; t++)
        acc[t] = __builtin_amdgcn_mfma_f32_16x16x32_bf16(afr[ks], bfr[t][ks], acc[t], 0, 0, 0);
    const int o0 = mt * 16 + 4 * qd;
    float4 bv = *(const float4*)(qb + o0);
    const int s3 = o0 / 96, om = o0 - s3 * 96, hh = om / 24, dd = om - hh * 24;
    if (s3 < 2){
      const float sc = (s3 == 0) ? (SCALE * LOG2E) : 1.f;
      unsigned short* hb = ((s3 == 0) ? qS : kS) + ((size_t)(w * 4 + hh)) * 8232 + dd;
      #pragma unroll
      for (int t = 0; t < 3; t++){
        if (nts[t] < 0 || toks[t] >= NTOK) continue;
        uint2 st;
        st.x = pkrn((acc[t][0] + bv.x) * sc, (acc[t][1] + bv.y) * sc);
        st.y = pkrn((acc[t][2] + bv.z) * sc, (acc[t][3] + bv.w) * sc);
        *(uint2*)(hb + (size_t)toks[t] * 24) = st;
      }
    } else {
      unsigned short* hb = vT + ((size_t)(w * 4 + hh)) * 8256 + (size_t)dd * 344;
      #pragma unroll
      for (int t = 0; t < 3; t++){
        if (nts[t] < 0 || toks[t] >= NTOK) continue;
        hb[0 * 344 + toks[t]] = f2bf(acc[t][0] + bv.x);
        hb[1 * 344 + toks[t]] = f2bf(acc[t][1] + bv.y);
        hb[2 * 344 + toks[t]] = f2bf(acc[t][2] + bv.z);
        hb[3 * 344 + toks[t]] = f2bf(acc[t][3] + bv.w);
      }
    }
  }
}

// ---------------- K2: MFMA attention (per window, head) ----------------
__global__ __launch_bounds__(256, 4) void k_attn(
    const unsigned short* __restrict__ qS, const unsigned short* __restrict__ kS,
    const unsigned short* __restrict__ vT, const unsigned short* __restrict__ rpbH,
    unsigned short* __restrict__ aO)
{
  __shared__ __align__(16) unsigned short VTsh[25 * VSTR];   // 18,000 B (row 24 = ones)
  __shared__ __align__(16) unsigned short Psh[4 * 16 * PSTR];
  __shared__ __align__(8) unsigned char lab8[NP];

  const int blk = blockIdx.x, w = blk >> 2, h = blk & 3;
  const int tid = threadIdx.x, lane = tid & 63, wv = tid >> 6;
  const int ln = lane & 15, qd = lane >> 4;

  {
    const unsigned* vg = (const unsigned*)(vT + (size_t)blk * 8256);
    unsigned* vd = (unsigned*)VTsh;
    for (int i = tid; i < 4128; i += 256){
      int d = i / 172, c = i - d * 172;
      vd[d * 180 + c] = vg[i];
    }
    for (int i = tid; i < 192; i += 256){
      int d = i >> 3, c = i & 7;
      vd[d * 180 + 172 + c] = 0u;
    }
    for (int i = tid; i < 180; i += 256) vd[24 * 180 + i] = 0x3f803f80u;
    const int wl = w & 63, wx = wl >> 4, wy = (wl >> 2) & 3, wz = wl & 3;
    for (int n = tid; n < NP; n += 256){
      int tx = n / 49, nm = n - tx * 49, ty = nm / 7, tz = nm - ty * 7;
      lab8[n] = (n < NTOK) ? (unsigned char)(region(wx*7+tx)*9 + region(wy*7+ty)*3 + region(wz*7+tz)) : (unsigned char)0;
    }
  }
  __syncthreads();

  bf16x8 qf[6];
  int labQ[6], qts[6];
  #pragma unroll
  for (int t = 0; t < 6; t++){
    int qtr = wv + 4 * t;
    bool val = qtr < 22;
    qts[t] = val ? qtr : -1;
    int qt = val ? qtr : 0;
    int query = qt * 16 + ln;
    uint4 qv = *(const uint4*)(qS + (size_t)blk * 8232 + (size_t)query * 24 + qd * 8);
    if (qd == 3){ qv.x = 0; qv.y = 0; qv.z = 0; qv.w = 0; }
    qf[t] = __builtin_bit_cast(bf16x8, qv);
    labQ[t] = lab8[qt * 16 + ln];
  }

  f32x4 accO[6][2];
  #pragma unroll
  for (int t = 0; t < 6; t++)
    #pragma unroll
    for (int d2 = 0; d2 < 2; d2++){ accO[t][d2][0]=0.f; accO[t][d2][1]=0.f; accO[t][d2][2]=0.f; accO[t][d2][3]=0.f; }

  const unsigned short* biasBase = rpbH + (size_t)h * (11 * 22 * 512);
  unsigned short* pb = Psh + wv * 16 * PSTR + ln * PSTR;
  const unsigned short* pr = Psh + wv * 16 * PSTR + ln * PSTR + qd * 8;
  const int vrow1 = (ln < 8) ? (16 + ln) : 24;
  const size_t kbase = (size_t)blk * 8232;

  for (int kp = 0; kp < 11; kp++){
    uint4 kv0 = *(const uint4*)(kS + kbase + (size_t)(kp * 32 + ln) * 24 + qd * 8);
    uint4 kv1 = *(const uint4*)(kS + kbase + (size_t)(kp * 32 + 16 + ln) * 24 + qd * 8);
    bf16x8 kf0 = __builtin_bit_cast(bf16x8, kv0);
    bf16x8 kf1 = __builtin_bit_cast(bf16x8, kv1);
    bf16x8 vf0 = *(const bf16x8*)(VTsh + ln * VSTR + kp * 32 + qd * 8);
    bf16x8 vf1 = *(const bf16x8*)(VTsh + vrow1 * VSTR + kp * 32 + qd * 8);
    const unsigned* l32 = (const unsigned*)lab8;
    unsigned la = l32[kp * 8 + qd];
    unsigned lb = l32[kp * 8 + 4 + qd];
    int kl0[4], kl1[4];
    #pragma unroll
    for (int r = 0; r < 4; r++){ kl0[r] = (la >> (8 * r)) & 255; kl1[r] = (lb >> (8 * r)) & 255; }

    #pragma unroll
    for (int t = 0; t < 6; t++){
      if (qts[t] < 0) continue;
      const int qt = qts[t];
      uint4 bv = *(const uint4*)(biasBase + (((size_t)kp * 22 + qt) * 64 + lane) * 8);
      f32x4 C0, C1;
      C0[0] = bflo(bv.x); C0[1] = bfhi(bv.x); C0[2] = bflo(bv.y); C0[3] = bfhi(bv.y);
      C1[0] = bflo(bv.z); C1[1] = bfhi(bv.z); C1[2] = bflo(bv.w); C1[3] = bfhi(bv.w);
      f32x4 s0 = __builtin_amdgcn_mfma_f32_16x16x32_bf16(kf0, qf[t], C0, 0, 0, 0);
      f32x4 s1 = __builtin_amdgcn_mfma_f32_16x16x32_bf16(kf1, qf[t], C1, 0, 0, 0);
      const int lq = labQ[t];
      float e0[4], e1[4];
      #pragma unroll
      for (int r = 0; r < 4; r++){
        float ev = __builtin_amdgcn_exp2f(s0[r]);
        e0[r] = (kl0[r] == lq) ? ev : 0.f;
      }
      #pragma unroll
      for (int r = 0; r < 4; r++){
        float ev = __builtin_amdgcn_exp2f(s1[r]);
        e1[r] = (kl1[r] == lq) ? ev : 0.f;
      }
      uint2 w0; w0.x = pk2(e0[0], e0[1]); w0.y = pk2(e0[2], e0[3]);
      uint2 w1; w1.x = pk2(e1[0], e1[1]); w1.y = pk2(e1[2], e1[3]);
      *(uint2*)(pb + 4 * qd)      = w0;
      *(uint2*)(pb + 16 + 4 * qd) = w1;
      bf16x8 pf = *(const bf16x8*)pr;
      accO[t][0] = __builtin_amdgcn_mfma_f32_16x16x32_bf16(vf0, pf, accO[t][0], 0, 0, 0);
      accO[t][1] = __builtin_amdgcn_mfma_f32_16x16x32_bf16(vf1, pf, accO[t][1], 0, 0, 0);
    }
  }

  #pragma unroll
  for (int t = 0; t < 6; t++){
    if (qts[t] < 0) continue;
    float ss = __shfl(accO[t][1][0], 32 + ln);
    float inv = 1.f / ss;
    int query = qts[t] * 16 + ln;
    if (query < NTOK){
      unsigned short* dst = aO + (size_t)w * 32928 + (size_t)query * 96 + h * 24;
      uint2 o0;
      o0.x = pkrn(accO[t][0][0] * inv, accO[t][0][1] * inv);
      o0.y = pkrn(accO[t][0][2] * inv, accO[t][0][3] * inv);
      *(uint2*)(dst + 4 * qd) = o0;
      if (qd < 2){
        uint2 o1;
        o1.x = pkrn(accO[t][1][0] * inv, accO[t][1][1] * inv);
        o1.y = pkrn(accO[t][1][2] * inv, accO[t][1][3] * inv);
        *(uint2*)(dst + 16 + 4 * qd) = o1;
      }
    }
  }
}

// ---------------- K3: MFMA proj + window-reverse + un-shift + residual ----------------
__global__ __launch_bounds__(256, 4) void k_proj(
    const unsigned short* __restrict__ aO, const unsigned short* __restrict__ wP,
    const float* __restrict__ pb, const float* __restrict__ x, float* __restrict__ out)
{
  __shared__ __align__(16) unsigned short aF[11 * 12 * 16 * 8];   // 33,792 B
  const int blk = blockIdx.x, w = blk >> 1, half = blk & 1;
  const int b = w >> 6, wl = w & 63;
  const int wx = wl >> 4, wy = (wl >> 2) & 3, wz = wl & 3;
  const int tid = threadIdx.x, lane = tid & 63, wv = tid >> 6;

  for (int i = tid; i < 2112; i += 256){
    int r = i / 12, kq = i - r * 12;
    int tl = half * 176 + r;
    uint4 v;
    if (tl < NTOK) v = *(const uint4*)(aO + (size_t)w * 32928 + (size_t)tl * 96 + kq * 8);
    else { v.x = 0u; v.y = 0u; v.z = 0u; v.w = 0u; }
    int nt = r >> 4, n = r & 15;
    *(uint4*)(aF + ((nt * 12 + kq) * 16 + n) * 8) = v;
  }
  __syncthreads();

  const int ln = lane & 15, qd = lane >> 4;
  bf16x8 bfr[3][3];
  int nts[3]; size_t oi[3]; bool tv[3];
  #pragma unroll
  for (int t = 0; t < 3; t++){
    int nt = wv + 4 * t;
    nts[t] = (nt < 11) ? nt : -1;
    int ntc = (nt < 11) ? nt : 0;
    int tok = half * 176 + ntc * 16 + ln;
    tv[t] = (nts[t] >= 0) && (tok < NTOK);
    int tk = (tok < NTOK) ? tok : 0;
    int tx = tk / 49, rm = tk - tx * 49, ty = rm / 7, tz = rm - ty * 7;
    int sx = (wx * 7 + tx + 3) % 28, sy = (wy * 7 + ty + 3) % 28, sz = (wz * 7 + tz + 3) % 28;
    oi[t] = ((size_t)b * 21952 + ((sx * 28 + sy) * 28 + sz)) * 96;
    #pragma unroll
    for (int ks = 0; ks < 3; ks++)
      bfr[t][ks] = *(const bf16x8*)(aF + ((ntc * 12 + ks * 4 + qd) * 16 + ln) * 8);
  }
  for (int mt = 0; mt < 6; mt++){
    bf16x8 afr[3];
    #pragma unroll
    for (int ks = 0; ks < 3; ks++)
      afr[ks] = *(const bf16x8*)(wP + ((mt * 12 + ks * 4 + qd) * 16 + ln) * 8);
    f32x4 acc[3];
    #pragma unroll
    for (int t = 0; t < 3; t++){ acc[t][0] = 0.f; acc[t][1] = 0.f; acc[t][2] = 0.f; acc[t][3] = 0.f; }
    #pragma unroll
    for (int ks = 0; ks < 3; ks++)
      #pragma unroll
      for (int t = 0; t < 3; t++)
        acc[t] = __builtin_amdgcn_mfma_f32_16x16x32_bf16(afr[ks], bfr[t][ks], acc[t], 0, 0, 0);
    const int c0 = mt * 16 + 4 * qd;
    float4 bv = *(const float4*)(pb + c0);
    #pragma unroll
    for (int t = 0; t < 3; t++){
      if (!tv[t]) continue;
      float4 cur = *(const float4*)(x + oi[t] + c0);
      float4 o;
      o.x = acc[t][0] + bv.x + cur.x;
      o.y = acc[t][1] + bv.y + cur.y;
      o.z = acc[t][2] + bv.z + cur.z;
      o.w = acc[t][3] + bv.w + cur.w;
      *(float4*)(out + oi[t] + c0) = o;
    }
  }
}

// ---------------- K4a: LN2 + fc1 + GeLU -> hid (256 tokens/block, weights in registers) -------
// hid layout: [NT][48][16][8] = fc2 B-frag order, NT = global 16-token tile (0..5487)
__global__ __launch_bounds__(512, 4) void k_fc1(
    const float* __restrict__ io, const float* __restrict__ n2w, const float* __restrict__ n2b,
    const unsigned short* __restrict__ w1F, const float* __restrict__ b1g,
    unsigned short* __restrict__ hid)
{
  __shared__ __align__(16) unsigned short xnF[16 * 12 * 16 * 8];   // 49,152 B
  const int tid = threadIdx.x, lane = tid & 63, wv = tid >> 6;     // 8 waves
  const size_t row0 = (size_t)blockIdx.x * 256;

  const float g1 = n2w[lane], c1 = n2b[lane];
  const float g2 = (lane < 32) ? n2w[64 + lane] : 0.f;
  const float c2 = (lane < 32) ? n2b[64 + lane] : 0.f;
  for (int r = wv; r < 256; r += 8){
    const float* xr = io + (row0 + r) * 96;
    float v1 = xr[lane], v2 = (lane < 32) ? xr[64 + lane] : 0.f;
    float s = v1 + v2, sq = v1 * v1 + v2 * v2;
    #pragma unroll
    for (int off = 32; off; off >>= 1){ s += __shfl_xor(s, off); sq += __shfl_xor(sq, off); }
    float mu = s * (1.f / 96.f);
    float rs = rsqrtf(sq * (1.f / 96.f) - mu * mu + 1e-5f);
    int nt = r >> 4, n = r & 15;
    xnF[((nt * 12 + (lane >> 3)) * 16 + n) * 8 + (lane & 7)] = f2bf((v1 - mu) * rs * g1 + c1);
    if (lane < 32){
      int cc = 64 + lane;
      xnF[((nt * 12 + (cc >> 3)) * 16 + n) * 8 + (cc & 7)] = f2bf((v2 - mu) * rs * g2 + c2);
    }
  }
  __syncthreads();

  const int h = lane & 15, q = lane >> 4;
  // wave owns 3 m-tiles (24 total / 8 waves); A-frags held in registers for the whole block
  bf16x8 afr[3][3];
  float4 bv[3];
  #pragma unroll
  for (int i = 0; i < 3; i++){
    int mt = wv * 3 + i;
    #pragma unroll
    for (int ks = 0; ks < 3; ks++)
      afr[i][ks] = *(const bf16x8*)(w1F + ((mt * 12 + ks * 4 + q) * 16 + h) * 8);
    bv[i] = *(const float4*)(b1g + mt * 16 + 4 * q);
  }
  for (int nt = 0; nt < 16; nt++){
    bf16x8 bfr[3];
    #pragma unroll
    for (int ks = 0; ks < 3; ks++)
      bfr[ks] = *(const bf16x8*)(xnF + ((nt * 12 + ks * 4 + q) * 16 + h) * 8);
    f32x4 acc[3];
    #pragma unroll
    for (int i = 0; i < 3; i++){
      acc[i][0] = bv[i].x; acc[i][1] = bv[i].y; acc[i][2] = bv[i].z; acc[i][3] = bv[i].w;
    }
    #pragma unroll
    for (int ks = 0; ks < 3; ks++)
      #pragma unroll
      for (int i = 0; i < 3; i++)
        acc[i] = __builtin_amdgcn_mfma_f32_16x16x32_bf16(afr[i][ks], bfr[ks], acc[i], 0, 0, 0);
    const size_t NT = (size_t)blockIdx.x * 16 + nt;
    #pragma unroll
    for (int i = 0; i < 3; i++){
      int o0 = (wv * 3 + i) * 16 + 4 * q;
      float g0 = gelu_fast(acc[i][0]), g1v = gelu_fast(acc[i][1]);
      float g2v = gelu_fast(acc[i][2]), g3 = gelu_fast(acc[i][3]);
      unsigned short* d = hid + ((NT * 48 + (o0 >> 3)) * 16 + h) * 8 + (o0 & 7);
      uint2 pkv; pkv.x = pk2(g0, g1v); pkv.y = pk2(g2v, g3);
      *(uint2*)d = pkv;
    }
  }
}

// ---------------- K4b: fc2 + residual (256 tokens/block, w2 staged in LDS) ----------------
__global__ __launch_bounds__(512, 4) void k_fc2(
    float* __restrict__ io, const unsigned short* __restrict__ hid,
    const unsigned short* __restrict__ w2F, const float* __restrict__ b2g)
{
  __shared__ __align__(16) unsigned short w2sh[73728];   // 73,728 B -> 2 blocks/CU
  const int tid = threadIdx.x, lane = tid & 63, wv = tid >> 6;   // 8 waves
  {
    const uint2* src = (const uint2*)w2F;
    uint2* dst = (uint2*)w2sh;
    for (int i = tid; i < 18432; i += 512) dst[i] = src[i];
  }
  __syncthreads();

  const int h = lane & 15, q = lane >> 4;
  const int mh = wv >> 2, ntl = wv & 3;   // 3 m-tiles, 4 token tiles per wave
  float4 bv[3];
  #pragma unroll
  for (int i = 0; i < 3; i++) bv[i] = *(const float4*)(b2g + (mh * 3 + i) * 16 + 4 * q);

  f32x4 acc[3][4];
  #pragma unroll
  for (int i = 0; i < 3; i++)
    #pragma unroll
    for (int j = 0; j < 4; j++){
      acc[i][j][0] = bv[i].x; acc[i][j][1] = bv[i].y; acc[i][j][2] = bv[i].z; acc[i][j][3] = bv[i].w;
    }

  const size_t NT0 = (size_t)blockIdx.x * 16;
  for (int ks = 0; ks < 12; ks++){
    bf16x8 afr[3];
    #pragma unroll
    for (int i = 0; i < 3; i++)
      afr[i] = *(const bf16x8*)(w2sh + (((mh * 3 + i) * 48 + ks * 4 + q) * 16 + h) * 8);
    bf16x8 bfr[4];
    #pragma unroll
    for (int j = 0; j < 4; j++){
      size_t NT = NT0 + ntl + 4 * j;
      bfr[j] = *(const bf16x8*)(hid + ((NT * 48 + ks * 4 + q) * 16 + h) * 8);
    }
    #pragma unroll
    for (int j = 0; j < 4; j++)
      #pragma unroll
      for (int i = 0; i < 3; i++)
        acc[i][j] = __builtin_amdgcn_mfma_f32_16x16x32_bf16(afr[i], bfr[j], acc[i][j], 0, 0, 0);
  }

  #pragma unroll
  for (int j = 0; j < 4; j++){
    float* orow = io + ((NT0 + ntl + 4 * j) * 16 + h) * 96;
    #pragma unroll
    for (int i = 0; i < 3; i++){
      int c0 = (mh * 3 + i) * 16 + 4 * q;
      float4 cur = *(const float4*)(orow + c0);
      cur.x += acc[i][j][0]; cur.y += acc[i][j][1]; cur.z += acc[i][j][2]; cur.w += acc[i][j][3];
      *(float4*)(orow + c0) = cur;
    }
  }
}

extern "C" void kernel_launch(void* const* d_in, const int* in_sizes, int n_in,
                              void* d_out, int out_size, void* d_ws, size_t ws_size,
                              hipStream_t stream)
{
  const float* x      = (const float*)d_in[0];
  const float* n1w    = (const float*)d_in[1];
  const float* n1b    = (const float*)d_in[2];
  const float* qkvw   = (const float*)d_in[3];
  const float* qkvb   = (const float*)d_in[4];
  const float* rpbtab = (const float*)d_in[5];
  const float* projw  = (const float*)d_in[6];
  const float* projb  = (const float*)d_in[7];
  const float* n2w    = (const float*)d_in[8];
  const float* n2b    = (const float*)d_in[9];
  const float* fc1w   = (const float*)d_in[10];
  const float* fc1b   = (const float*)d_in[11];
  const float* fc2w   = (const float*)d_in[12];
  const float* fc2b   = (const float*)d_in[13];
  float* out = (float*)d_out;

  // workspace (halves): qS 8,429,568 | kS 8,429,568 | vT 8,454,144 | aO 8,429,568 | rpbH 495,616
  unsigned short* qS   = (unsigned short*)d_ws;
  unsigned short* kS   = qS + 8429568;
  unsigned short* vT   = kS + 8429568;
  unsigned short* aO   = vT + 8454144;
  unsigned short* rpbH = aO + 8429568;
  unsigned short* wQ  = aO;                 // alias: dead until k_attn writes aO
  unsigned short* w1F = qS;                 // aliases: dead after k_attn reads qS
  unsigned short* w2F = qS + 36864;
  unsigned short* wP  = qS + 73728;
  // hid (33,718,272 shorts) aliases everything after the weight frags; rpbH/kS/vT/aO all
  // dead by the time k_fc1 runs. Pool after qS+82944 is 34,155,520 shorts — fits.
  unsigned short* hid = qS + 82944;

  k_rpb   <<<dim3(968),  dim3(256), 0, stream>>>(rpbtab, rpbH);
  k_wprep1<<<dim3(108),  dim3(256), 0, stream>>>(qkvw, wQ);
  k_qkv   <<<dim3(512),  dim3(256), 0, stream>>>(x, n1w, n1b, wQ, qkvb, qS, kS, vT);
  k_attn  <<<dim3(1024), dim3(256), 0, stream>>>(qS, kS, vT, rpbH, aO);
  k_wprep2<<<dim3(324),  dim3(256), 0, stream>>>(projw, fc1w, fc2w, w1F, w2F, wP);
  k_proj  <<<dim3(512),  dim3(256), 0, stream>>>(aO, wP, projb, x, out);
  k_fc1   <<<dim3(343),  dim3(512), 0, stream>>>(out, n2w, n2b, w1F, fc1b, hid);
  k_fc2   <<<dim3(343),  dim3(512), 0, stream>>>(out, hid, w2F, fc2b);
}